// Round 8
// baseline (3661.054 us; speedup 1.0000x reference)
//
#include <hip/hip_runtime.h>
#include <math.h>

#define MU_F 0.1f
#define SHRINK_F 0.01f   // LMBD * MU
#define BN_EPS_F 1e-5f

typedef _Float16 half_t;
typedef _Float16 half8 __attribute__((ext_vector_type(8)));
typedef float f32x4 __attribute__((ext_vector_type(4)));

// async global->LDS, 16B per lane. LDS dest is wave-uniform base + lane*16.
__device__ __forceinline__ void gll16(const half_t* g, half_t* l) {
    __builtin_amdgcn_global_load_lds(
        (const __attribute__((address_space(1))) void*)g,
        (__attribute__((address_space(3))) void*)l, 16, 0, 0);
}

// counted-vmcnt wait + raw barrier (verified idiom; rule #18 hygiene).
#define VM_WAIT_BARRIER(N) do {                                   \
    asm volatile("s_waitcnt vmcnt(" #N ")" ::: "memory");         \
    __builtin_amdgcn_s_barrier();                                 \
    __builtin_amdgcn_sched_barrier(0);                            \
} while (0)

// ---------------------------------------------------------------------------
// MFMA implicit-GEMM conv v8.
// Empirical law (r0-r7): wall = staged bytes / rate; rate ~4 TB/s at 6
// waves/CU, ~6 TB/s at 12 waves/CU (r2, m97). So: cut bytes AND run 12 w/CU.
//  - Tile 128co x 128px, EIGHT waves (512 thr, wave = 64co x 32px) ->
//    392 blocks = 12.25 waves/CU.
//  - HALO path (KS==3 && S==1; all Gram + stage-B convs): per ci-chunk stage
//    a flat 256-px halo ONCE (2 gll16/wave, 16KB, ring-2), serve all 9 taps
//    from LDS: lane index = px + dh*W + dw - (p0-48); per-tap validity
//    ((unsigned)(ph+dh)<H && (unsigned)(pw+dw)<W) -> cndmask 0, so flat-index
//    wraps are never selected. B staging 9x less (226 -> 50 MB/conv).
//    A: [flat=cc*9+tap][co][32] contiguous 8KB chunks, 1 gll16/wave, ring-4,
//    lookahead 3. vmcnt ladder (derived from exact issue order; halo issued
//    at ti==4 rides the queue, auto-drained by A-ordering):
//      end-of-step N = nA + (ti in {4,5,6} && more-cc ? 2 : 0),
//      nA = 2 (f+3<total) / 1 (f+2<total) / 0.
//  - OLD path (S==2 or KS==1: conv#1, Wsc): per-tap B staging (r5 scheme),
//    A+B 1 instr each per wave per chunk, ring-3, lookahead 2, N=2/0.
// LDS 64KB: A 4x8KB + halo 2x16KB (old path reuses halo area as B ring-3).
// 16B-slot swizzle: physical slot p holds logical p^((row>>1)&3), applied on
// DMA SOURCE (dest linear) and on ds_read (rule 21); conflict-free A/B reads.
// Frag layout (16x16x32): A row=l&15, k=(l>>4)*8+j ; B col=l&15 same k;
// C/D col=l&15, row=(l>>4)*4+reg  [m89-verified].
// edge_defer/out2F: Gram plumbing (round 5). NPX=25088=196*128 exact.
// ---------------------------------------------------------------------------
template<int KS, int S, int PAD, int MODE>
__global__ __launch_bounds__(512)
void conv_big(const half_t* __restrict__ Ag, const half_t* __restrict__ Xh,
              float* __restrict__ outF, half_t* __restrict__ outH,
              const half_t* __restrict__ auxH, const float* __restrict__ auxF,
              int CA, int Cout, int Hin, int Win, int Hout, int Wout, int ptiles,
              float alpha, float beta, float delta, int relu1,
              const float* __restrict__ pscale, const float* __restrict__ pbias,
              const float* __restrict__ aux3, int relu2,
              const half_t* __restrict__ zpg, int edge_defer,
              float* __restrict__ out2F)
{
    constexpr bool HALO = (KS == 3 && S == 1);
    __shared__ __align__(16) half_t sm[32768];   // 64 KB: A 4x4096h + B/halo 16384h

    const int tid = threadIdx.x;
    const int wv = tid >> 6, ln = tid & 63;
    const int co0 = blockIdx.y * 128;
    const int wco = (wv & 1) * 64, wpx = (wv >> 1) * 32;
    (void)ptiles;

    // bijective XCD swizzle (m204)
    int bx;
    {
        const int nwg = gridDim.x;
        const int q = nwg >> 3, r8 = nwg & 7;
        const int xcd = blockIdx.x & 7, idx = blockIdx.x >> 3;
        bx = (xcd < r8 ? xcd * (q + 1) : r8 * (q + 1) + (xcd - r8) * q) + idx;
    }
    const int p0 = bx * 128;

    const int PHW1 = Hout * Wout;
    const int NPX  = PHW1 * 32;

    const int fr = ln & 15, q8 = ln >> 4;
    const int sx = (q8 ^ ((fr >> 1) & 3)) << 3;   // read swizzle (row%16-based)

    const int cpt   = CA >> 5;
    const int total = KS * KS * cpt;

    // per-lane output geometry (2 px-groups per wave)
    int eph[2], epw[2], en2[2];
#pragma unroll
    for (int t2 = 0; t2 < 2; ++t2) {
        int px = p0 + wpx + t2 * 16 + fr;         // < NPX (exact tiling)
        en2[t2] = px / PHW1; int rem = px - en2[t2] * PHW1;
        eph[t2] = rem / Wout; epw[t2] = rem - eph[t2] * Wout;
    }

    // A chunk: contiguous 8KB at flat*Cout*32, 1 gll16/wave (row = tid>>2)
    auto issueA = [&](int flat, int slot) {
        const int row = tid >> 2;
        const int ssw = ((tid & 3) ^ ((row >> 1) & 3)) << 3;
        gll16(Ag + ((size_t)flat * Cout + co0 + row) * 32 + ssw,
              sm + slot * 4096 + tid * 8);
    };

    f32x4 acc[4][2] = {};

    if constexpr (HALO) {
        // halo: 256 px (p0-48 .. p0+207), 16KB, 2 gll16/wave
        auto issueH = [&](int cc, int hslot) {
            half_t* hb = sm + 16384 + hslot * 8192;
            const int c0 = cc << 5;
#pragma unroll
            for (int p = 0; p < 2; ++p) {
                const int hrow = (tid >> 2) + p * 128;
                const int hpx = p0 - 48 + hrow;
                const int ssw = ((tid & 3) ^ ((hrow >> 1) & 3)) << 3;
                const half_t* src = ((unsigned)hpx < (unsigned)NPX)
                    ? Xh + (size_t)hpx * CA + c0 + ssw : zpg;
                gll16(src, hb + p * 4096 + tid * 8);
            }
        };

        // prologue: H(0), A(0..2); need H0,A0 -> allow A1,A2
        issueH(0, 0);
        issueA(0, 0); issueA(1, 1); issueA(2, 2);
        VM_WAIT_BARRIER(2);

        int f = 0;
        for (int cc = 0; cc < cpt; ++cc) {
            half_t* hb = sm + 16384 + (cc & 1) * 8192;
            for (int ti = 0; ti < 9; ++ti, ++f) {
                half_t* ab = sm + (f & 3) * 4096;
                if (f + 3 < total) issueA(f + 3, (f + 3) & 3);
                const bool moreH = (ti == 4) && (cc + 1 < cpt);
                if (moreH) issueH(cc + 1, (cc + 1) & 1);

                const int kh = (ti * 11) >> 5, kw = ti - 3 * kh;
                const int dh = (MODE == 0) ? kh - 1 : 1 - kh;
                const int dw = (MODE == 0) ? kw - 1 : 1 - kw;
                const int doff = dh * Win + dw;

                half8 fa[4], fb[2];
#pragma unroll
                for (int m = 0; m < 4; ++m)
                    fa[m] = *(const half8*)(ab + (wco + m * 16 + fr) * 32 + sx);
#pragma unroll
                for (int t2 = 0; t2 < 2; ++t2) {
                    const int hidx = wpx + t2 * 16 + fr + 48 + doff;
                    half8 v = *(const half8*)(hb + hidx * 32 +
                                 ((q8 ^ ((hidx >> 1) & 3)) << 3));
                    bool ok = (unsigned)(eph[t2] + dh) < (unsigned)Hin &&
                              (unsigned)(epw[t2] + dw) < (unsigned)Win;
                    half8 z = {};
                    fb[t2] = ok ? v : z;
                }
#pragma unroll
                for (int m = 0; m < 4; ++m)
#pragma unroll
                    for (int t2 = 0; t2 < 2; ++t2)
                        acc[m][t2] = __builtin_amdgcn_mfma_f32_16x16x32_f16(
                            fa[m], fb[t2], acc[m][t2], 0, 0, 0);

                // end-of-step wait: chunk f+1 (and, by queue order, halo)
                const int nA = (f + 3 < total) ? 2 : ((f + 2 < total) ? 1 : 0);
                if (ti >= 4 && ti <= 6 && cc + 1 < cpt) VM_WAIT_BARRIER(4);
                else if (nA == 2)                        VM_WAIT_BARRIER(2);
                else if (nA == 1)                        VM_WAIT_BARRIER(1);
                else if (f + 1 < total)                  VM_WAIT_BARRIER(0);
            }
        }
    } else {
        // OLD path: per-tap B staging (1 gll16/wave), ring-3, lookahead 2
        const int brow = tid >> 2;
        int bpx = p0 + brow;                      // < NPX
        int bn2 = bpx / PHW1; int brem = bpx - bn2 * PHW1;
        const int bph = brem / Wout, bpw = brem - (brem / Wout) * Wout;
        const size_t bnb = (size_t)bn2 * Hin * Win;

        auto issueB = [&](int flat, int slot) {
            int cc, ti;
            if (KS == 1) { cc = flat; ti = 0; }
            else         { cc = (flat * 57) >> 9; ti = flat - 9 * cc; }
            const int kh = (KS == 3) ? ((ti * 11) >> 5) : 0;
            const int kw = (KS == 3) ? (ti - 3 * kh) : 0;
            const int c0 = cc << 5;
            const int hh = bph * S - PAD + kh, ww2 = bpw * S - PAD + kw;
            const bool ok = (unsigned)hh < (unsigned)Hin &&
                            (unsigned)ww2 < (unsigned)Win;
            const int ssw = ((tid & 3) ^ ((brow >> 1) & 3)) << 3;
            const half_t* src = ok
                ? Xh + (bnb + (size_t)(hh * Win + ww2)) * CA + c0 + ssw : zpg;
            gll16(src, sm + 16384 + slot * 4096 + tid * 8);
        };

        issueA(0, 0); issueB(0, 0);
        issueA(1, 1); issueB(1, 1);
        VM_WAIT_BARRIER(2);

        for (int k = 0; k < total; ++k) {
            half_t* ab = sm + (k % 3) * 4096;
            half_t* bb = sm + 16384 + (k % 3) * 4096;
            if (k + 2 < total) { issueA(k + 2, (k + 2) % 3); issueB(k + 2, (k + 2) % 3); }
            half8 fa[4], fb[2];
#pragma unroll
            for (int m = 0; m < 4; ++m)
                fa[m] = *(const half8*)(ab + (wco + m * 16 + fr) * 32 + sx);
#pragma unroll
            for (int t2 = 0; t2 < 2; ++t2)
                fb[t2] = *(const half8*)(bb + (wpx + t2 * 16 + fr) * 32 + sx);
#pragma unroll
            for (int m = 0; m < 4; ++m)
#pragma unroll
                for (int t2 = 0; t2 < 2; ++t2)
                    acc[m][t2] = __builtin_amdgcn_mfma_f32_16x16x32_f16(
                        fa[m], fb[t2], acc[m][t2], 0, 0, 0);
            if (k + 2 < total)      VM_WAIT_BARRIER(2);
            else if (k + 1 < total) VM_WAIT_BARRIER(0);
        }
    }

    // epilogue: wave 64co x 32px; lane 2x4x4 = 32 outputs
#pragma unroll
    for (int t = 0; t < 2; ++t) {
        const int oh = eph[t], ow = epw[t], n2 = en2[t];
        size_t ghwc = ((size_t)(n2 * Hout + oh) * Wout + ow) * Cout;
        bool defer = edge_defer && (oh == 0 || ow == 0);
#pragma unroll
        for (int m = 0; m < 4; ++m) {
#pragma unroll
            for (int rr = 0; rr < 4; ++rr) {
                int co_l = co0 + wco + m * 16 + q8 * 4 + rr;
                size_t fidx = ((size_t)(n2 * Cout + co_l) * Hout + oh) * Wout + ow;
                float av = alpha * acc[m][t][rr];
                if (out2F) out2F[fidx] = av;
                float v = av + delta;
                if (auxH) v += beta * (float)auxH[ghwc + co_l];
                if (auxF) v += beta * auxF[fidx];
                if (!defer) {
                    if (relu1) v = fmaxf(v, 0.f);
                    if (pscale) v = pscale[co_l] * v + pbias[co_l];
                    if (aux3) v += aux3[fidx];
                    if (relu2) v = fmaxf(v, 0.f);
                }
                if (outH) outH[ghwc + co_l] = (half_t)v;
                else      outF[fidx] = v;
            }
        }
    }
}

// pack weights into [ci-chunk*KT+tap][co][32ci] (+ transpose for convT).
template<int KT>
__global__ __launch_bounds__(256)
void pack_w(const float* __restrict__ W, half_t* __restrict__ Wh,
            half_t* __restrict__ WTh, int Cin, int Cout, int do_norm)
{
    __shared__ float red[256];
    int co = blockIdx.x, tid = threadIdx.x;
    int CK = Cin * KT;
    const float* w = W + (size_t)co * CK;
    float inv = 1.f;
    if (do_norm) {
        float s = 0.f;
        for (int i = tid; i < CK; i += 256) { float v = w[i]; s += v * v; }
        red[tid] = s; __syncthreads();
        for (int o = 128; o > 0; o >>= 1) {
            if (tid < o) red[tid] += red[tid + o];
            __syncthreads();
        }
        inv = 1.f / (sqrtf(red[0]) + 1e-12f);
    }
    for (int i = tid; i < CK; i += 256) {
        int ci = i / KT, tap = i - ci * KT;
        half_t h = (half_t)(w[i] * inv);
        Wh[(((size_t)(ci >> 5) * KT + tap) * Cout + co) * 32 + (ci & 31)] = h;
        if (WTh) WTh[(((size_t)(co >> 5) * KT + tap) * Cin + ci) * 32 + (co & 31)] = h;
    }
}

// Gram precompute (round 5): Gp in [b-chunk*9+tap][co][32b]; edge tensors.
__global__ __launch_bounds__(256)
void gram_kernel(const half_t* __restrict__ Wh, half_t* __restrict__ Gp,
                 half_t* __restrict__ ChT, half_t* __restrict__ CwT,
                 half_t* __restrict__ CcT)
{
    __shared__ float Wa[9 * 128];
    int co = blockIdx.x, b = threadIdx.x;
    for (int i = b; i < 9 * 128; i += 256) Wa[i] = (float)Wh[(size_t)co * 9 * 128 + i];
    __syncthreads();
    const half_t* Wb = Wh + (size_t)b * 9 * 128;
    auto dot = [&](int tA, int tB) {
        float s = 0.f;
        for (int c = 0; c < 128; ++c) s += Wa[tA * 128 + c] * (float)Wb[tB * 128 + c];
        return s;
    };
    auto lo = [](int t) { return (t == 2) ? 2 : 0; };
    auto hi = [](int t) { return (t == 1) ? 3 : ((t == 2) ? 3 : 1); };
    for (int th = 0; th < 3; ++th)
        for (int tw = 0; tw < 3; ++tw) {
            float s = 0.f;
            for (int kh = lo(th); kh < hi(th); ++kh)
                for (int kw = lo(tw); kw < hi(tw); ++kw)
                    s += dot(kh * 3 + kw, (kh + 2 - 2 * th) * 3 + (kw + 2 - 2 * tw));
            Gp[(((size_t)(b >> 5) * 9 + th * 3 + tw) * 256 + co) * 32 + (b & 31)] = (half_t)s;
        }
    for (int tw = 0; tw < 3; ++tw) {
        float s = 0.f, s2 = 0.f;
        for (int k = lo(tw); k < hi(tw); ++k) {
            s  += dot(k, k + 2 - 2 * tw);
            s2 += dot(k * 3, (k + 2 - 2 * tw) * 3);
        }
        ChT[((size_t)tw * 256 + b) * 256 + co] = (half_t)s;
        CwT[((size_t)tw * 256 + b) * 256 + co] = (half_t)s2;
    }
    CcT[(size_t)b * 256 + co] = (half_t)dot(0, 0);
}

// raw [co][tap][ci] normalized pack (gram input only)
__global__ __launch_bounds__(256)
void pack_raw(const float* __restrict__ W, half_t* __restrict__ Wr, int CK)
{
    __shared__ float red[256];
    int co = blockIdx.x, tid = threadIdx.x;
    const float* w = W + (size_t)co * CK;
    float s = 0.f;
    for (int i = tid; i < CK; i += 256) { float v = w[i]; s += v * v; }
    red[tid] = s; __syncthreads();
    for (int o = 128; o > 0; o >>= 1) {
        if (tid < o) red[tid] += red[tid + o];
        __syncthreads();
    }
    float inv = 1.f / (sqrtf(red[0]) + 1e-12f);
    for (int i = tid; i < CK; i += 256) {
        int ci = i / 9, tap = i - ci * 9;
        Wr[((size_t)co * 9 + tap) * (CK / 9) + ci] = (half_t)(w[i] * inv);
    }
}

// boundary finisher, n-innermost (weights loaded ONCE per block, 32x less
// correction-matrix traffic than r5's per-(i,n)-block version).
__global__ __launch_bounds__(256)
void edge_fix(const half_t* __restrict__ a, half_t* out,
              const half_t* __restrict__ ChT, const half_t* __restrict__ CwT,
              const half_t* __restrict__ CcT,
              const float* __restrict__ ps, const float* __restrict__ pb)
{
    int i = blockIdx.x, co = threadIdx.x;
    int oh, ow;
    if (i < 28) { oh = 0; ow = i; } else { oh = i - 27; ow = 0; }
    float corr[32];
#pragma unroll
    for (int n = 0; n < 32; ++n) corr[n] = 0.f;
    if (oh == 0) {
        for (int kw = 0; kw < 3; ++kw) {
            int pw = ow - 1 + kw;
            if ((unsigned)pw < 28u) {
                const half_t* cp = ChT + (size_t)kw * 256 * 256 + co;
                for (int b2 = 0; b2 < 256; ++b2) {
                    float w = (float)cp[(size_t)b2 * 256];
#pragma unroll
                    for (int n = 0; n < 32; ++n)
                        corr[n] += w * (float)a[((size_t)(n * 28 + 0) * 28 + pw) * 256 + b2];
                }
            }
        }
    }
    if (ow == 0) {
        for (int kh = 0; kh < 3; ++kh) {
            int ph = oh - 1 + kh;
            if ((unsigned)ph < 28u) {
                const half_t* cp = CwT + (size_t)kh * 256 * 256 + co;
                for (int b2 = 0; b2 < 256; ++b2) {
                    float w = (float)cp[(size_t)b2 * 256];
#pragma unroll
                    for (int n = 0; n < 32; ++n)
                        corr[n] += w * (float)a[((size_t)(n * 28 + ph) * 28 + 0) * 256 + b2];
                }
            }
        }
    }
    if (oh == 0 && ow == 0) {
        for (int b2 = 0; b2 < 256; ++b2) {
            float w = (float)CcT[(size_t)b2 * 256 + co];
#pragma unroll
            for (int n = 0; n < 32; ++n)
                corr[n] -= w * (float)a[((size_t)(n * 28) * 28) * 256 + b2];
        }
    }
#pragma unroll
    for (int n = 0; n < 32; ++n) {
        size_t idx = ((size_t)(n * 28 + oh) * 28 + ow) * 256 + co;
        float v = (float)out[idx] + MU_F * corr[n];
        v = fmaxf(v, 0.f);
        if (ps) v = ps[co] * v + pb[co];
        out[idx] = (half_t)v;
    }
}

__global__ __launch_bounds__(256)
void tx_kernel(const float* __restrict__ x, half_t* __restrict__ xTh)
{
    __shared__ __align__(16) half_t tl[56 * 136];
    int h = blockIdx.x, n = blockIdx.y, tid = threadIdx.x;
    for (int it = 0; it < 28; ++it) {
        int id = tid + it * 256;
        int c = id / 56, w0 = id - c * 56;
        tl[w0 * 136 + c] = (half_t)x[(((size_t)n * 128 + c) * 56 + h) * 56 + w0];
    }
    __syncthreads();
    if (tid < 224) {
        int w0 = tid >> 2, part = tid & 3;
        size_t base = (((size_t)n * 56 + h) * 56 + w0) * 128 + part * 32;
#pragma unroll
        for (int j = 0; j < 4; ++j)
            *(half8*)(xTh + base + j * 8) = *(const half8*)(tl + w0 * 136 + part * 32 + j * 8);
    }
}

__global__ __launch_bounds__(256)
void comb_kernel(const half_t* __restrict__ c, const half_t* __restrict__ p,
                 half_t* __restrict__ a, float w1, float w2, int n8)
{
    int i = blockIdx.x * 256 + threadIdx.x;
    if (i >= n8) return;
    half8 cv = ((const half8*)c)[i];
    half8 pv = ((const half8*)p)[i];
    half8 rres;
#pragma unroll
    for (int j = 0; j < 8; ++j) rres[j] = (half_t)(w1 * (float)cv[j] + w2 * (float)pv[j]);
    ((half8*)a)[i] = rres;
}

__global__ __launch_bounds__(256)
void bn_prep_kernel(const float* __restrict__ g, const float* __restrict__ b,
                    const float* __restrict__ m, const float* __restrict__ v,
                    float* __restrict__ s, float* __restrict__ t, int C)
{
    int i = blockIdx.x * 256 + threadIdx.x;
    if (i < C) {
        float sc = g[i] * rsqrtf(v[i] + BN_EPS_F);
        s[i] = sc; t[i] = b[i] - m[i] * sc;
    }
}

__global__ __launch_bounds__(128)
void zfill_kernel(half_t* __restrict__ p)
{
    p[threadIdx.x] = (half_t)0.f;
}

extern "C" void kernel_launch(void* const* d_in, const int* in_sizes, int n_in,
                              void* d_out, int out_size, void* d_ws, size_t ws_size,
                              hipStream_t stream)
{
    (void)in_sizes; (void)n_in; (void)out_size;
    const float* x    = (const float*)d_in[0];
    const float* W1   = (const float*)d_in[1];
    const float* W2   = (const float*)d_in[2];
    const float* Wsc  = (const float*)d_in[3];
    const float* bn1g = (const float*)d_in[4];
    const float* bn1b = (const float*)d_in[5];
    const float* bn1m = (const float*)d_in[6];
    const float* bn1v = (const float*)d_in[7];
    const float* bn2g = (const float*)d_in[8];
    const float* bn2b = (const float*)d_in[9];
    const float* bn2m = (const float*)d_in[10];
    const float* bn2v = (const float*)d_in[11];
    const float* bscg = (const float*)d_in[12];
    const float* bscb = (const float*)d_in[13];
    const float* bscm = (const float*)d_in[14];
    const float* bscv = (const float*)d_in[15];

    const size_t NB = (size_t)32 * 256 * 28 * 28;
    const size_t NX = (size_t)32 * 128 * 56 * 56;

    char* base = (char*)d_ws;
    size_t off = 0;
    auto alloc = [&](size_t nbytes) -> void* {
        void* r = base + off;
        off = (off + nbytes + 255) & ~(size_t)255;
        return r;
    };
    half_t* Wh1  = (half_t*)alloc(294912 * 2);
    half_t* Wr1  = (half_t*)alloc(294912 * 2);
    half_t* Wh2  = (half_t*)alloc(589824 * 2);
    half_t* WTh2 = (half_t*)alloc(589824 * 2);
    half_t* Wsch = (half_t*)alloc(32768 * 2);
    half_t* Gph  = (half_t*)alloc(589824 * 2);
    half_t* ChT  = (half_t*)alloc(196608 * 2);
    half_t* CwT  = (half_t*)alloc(196608 * 2);
    half_t* CcT  = (half_t*)alloc(65536 * 2);
    float* bn1s = (float*)alloc(256 * 4);  float* bn1t = (float*)alloc(256 * 4);
    float* bn2s = (float*)alloc(256 * 4);  float* bn2t = (float*)alloc(256 * 4);
    float* bscs = (float*)alloc(256 * 4);  float* bsct = (float*)alloc(256 * 4);
    half_t* zpg  = (half_t*)alloc(256);
    half_t* xTh  = (half_t*)alloc(NX * 2);
    half_t* Pa   = (half_t*)alloc(NB * 2);
    half_t* Pb   = (half_t*)alloc(NB * 2);
    half_t* Pc   = (half_t*)alloc(NB * 2);
    half_t* Py   = (half_t*)alloc(NB * 2);
    half_t* r28h = (half_t*)alloc(NB * 2);
    float*  scF  = (float*)alloc(NB * 4);
    if (off > ws_size) return;

    float*  cxF = (float*)Py;    // fp32 NCHW cache over Py+r28h (dead in stage A)
    half_t* Pd  = (half_t*)xTh;  // stage-B temp over xTh (dead in stage B)

    float* outp = (float*)d_out;

    double t = 1.0; float al[3];
    for (int i = 0; i < 3; ++i) {
        double tn = (1.0 + sqrt(1.0 + 4.0 * t * t)) / 2.0;
        al[i] = (float)((t - 1.0) / tn); t = tn;
    }

    const dim3 blk(256);
    const dim3 cblk(512);          // 8 waves
    const dim3 gB(196, 2, 1);      // 25088/128 px-tiles x 2 co-halves
    const dim3 gE(55, 1, 1);
    const int n8 = (int)(NB / 8);
    const dim3 gC((n8 + 255) / 256);
    const float* NF = nullptr;
    const half_t* NH = nullptr;
    float* NFo = nullptr;
    half_t* NHo = nullptr;

    pack_w<9><<<256, blk, 0, stream>>>(W1, Wh1, nullptr, 128, 256, 1);
    pack_raw<<<256, blk, 0, stream>>>(W1, Wr1, 128 * 9);
    pack_w<9><<<256, blk, 0, stream>>>(W2, Wh2, WTh2, 256, 256, 1);
    pack_w<1><<<256, blk, 0, stream>>>(Wsc, Wsch, nullptr, 128, 256, 0);
    gram_kernel<<<256, blk, 0, stream>>>(Wr1, Gph, ChT, CwT, CcT);
    bn_prep_kernel<<<1, blk, 0, stream>>>(bn1g, bn1b, bn1m, bn1v, bn1s, bn1t, 256);
    bn_prep_kernel<<<1, blk, 0, stream>>>(bn2g, bn2b, bn2m, bn2v, bn2s, bn2t, 256);
    bn_prep_kernel<<<1, blk, 0, stream>>>(bscg, bscb, bscm, bscv, bscs, bsct, 256);
    zfill_kernel<<<1, dim3(128), 0, stream>>>(zpg);
    tx_kernel<<<dim3(56, 32), blk, 0, stream>>>(x, xTh);

    // ============ Stage A: dict_conv(x, W1, stride 2) — Gram form ==========
    conv_big<3,2,1,0><<<gB, cblk, 0, stream>>>(Wh1, xTh, NFo, Pa, NH, NF,
        128, 256, 56, 56, 28, 28, 196, MU_F, 0.f, -SHRINK_F, 1, NF, NF, NF, 0, zpg, 0, cxF);
    conv_big<1,2,0,0><<<gB, cblk, 0, stream>>>(Wsch, xTh, scF, NHo, NH, NF,
        128, 256, 56, 56, 28, 28, 196, 1.f, 0.f, 0.f, 0, bscs, bsct, NF, 0, zpg, 0, NFo);

    conv_big<3,1,1,0><<<gB, cblk, 0, stream>>>(Gph, Pa, NFo, Pb, Pa, cxF,
        256, 256, 28, 28, 28, 28, 196, -MU_F, 1.f, -SHRINK_F, 1, NF, NF, NF, 0, zpg, 1, NFo);
    edge_fix<<<gE, blk, 0, stream>>>(Pa, Pb, ChT, CwT, CcT, NF, NF);

    comb_kernel<<<gC, blk, 0, stream>>>(Pb, Pa, Pc, 1.f + al[1], -al[1], n8);
    conv_big<3,1,1,0><<<gB, cblk, 0, stream>>>(Gph, Pc, NFo, Pa, Pc, cxF,
        256, 256, 28, 28, 28, 28, 196, -MU_F, 1.f, -SHRINK_F, 1, NF, NF, NF, 0, zpg, 1, NFo);
    edge_fix<<<gE, blk, 0, stream>>>(Pc, Pa, ChT, CwT, CcT, NF, NF);

    comb_kernel<<<gC, blk, 0, stream>>>(Pa, Pb, Pc, 1.f + al[2], -al[2], n8);
    conv_big<3,1,1,0><<<gB, cblk, 0, stream>>>(Gph, Pc, NFo, Pb, Pc, cxF,
        256, 256, 28, 28, 28, 28, 196, -MU_F, 1.f, -SHRINK_F, 1, bn1s, bn1t, NF, 0, zpg, 1, NFo);
    edge_fix<<<gE, blk, 0, stream>>>(Pc, Pb, ChT, CwT, CcT, bn1s, bn1t);

    // ================= Stage B: dict_conv(y1=Pb, W2, stride 1) =============
    conv_big<3,1,1,0><<<gB, cblk, 0, stream>>>(Wh2, Pb, NFo, Pa, NH, NF,
        256, 256, 28, 28, 28, 28, 196, MU_F, 0.f, -SHRINK_F, 1, NF, NF, NF, 0, zpg, 0, NFo);

    conv_big<3,1,1,1><<<gB, cblk, 0, stream>>>(WTh2, Pa, NFo, r28h, Pb, NF,
        256, 256, 28, 28, 28, 28, 196, -1.f, 1.f, 0.f, 0, NF, NF, NF, 0, zpg, 0, NFo);
    conv_big<3,1,1,0><<<gB, cblk, 0, stream>>>(Wh2, r28h, NFo, Pd, Pa, NF,
        256, 256, 28, 28, 28, 28, 196, MU_F, 1.f, -SHRINK_F, 1, NF, NF, NF, 0, zpg, 0, NFo);

    comb_kernel<<<gC, blk, 0, stream>>>(Pd, Pa, Pc, 1.f + al[1], -al[1], n8);
    conv_big<3,1,1,1><<<gB, cblk, 0, stream>>>(WTh2, Pc, NFo, r28h, Pb, NF,
        256, 256, 28, 28, 28, 28, 196, -1.f, 1.f, 0.f, 0, NF, NF, NF, 0, zpg, 0, NFo);
    conv_big<3,1,1,0><<<gB, cblk, 0, stream>>>(Wh2, r28h, NFo, Pa, Pc, NF,
        256, 256, 28, 28, 28, 28, 196, MU_F, 1.f, -SHRINK_F, 1, NF, NF, NF, 0, zpg, 0, NFo);

    comb_kernel<<<gC, blk, 0, stream>>>(Pa, Pd, Pc, 1.f + al[2], -al[2], n8);
    conv_big<3,1,1,1><<<gB, cblk, 0, stream>>>(WTh2, Pc, NFo, r28h, Pb, NF,
        256, 256, 28, 28, 28, 28, 196, -1.f, 1.f, 0.f, 0, NF, NF, NF, 0, zpg, 0, NFo);
    conv_big<3,1,1,0><<<gB, cblk, 0, stream>>>(Wh2, r28h, outp, NHo, Pc, NF,
        256, 256, 28, 28, 28, 28, 196, MU_F, 1.f, -SHRINK_F, 1, bn2s, bn2t, scF, 1, zpg, 0, NFo);
}

// Round 9
// 1192.168 us; speedup vs baseline: 3.0709x; 3.0709x over previous
//
#include <hip/hip_runtime.h>
#include <math.h>

#define MU_F 0.1f
#define SHRINK_F 0.01f   // LMBD * MU
#define BN_EPS_F 1e-5f

typedef _Float16 half_t;
typedef _Float16 half8 __attribute__((ext_vector_type(8)));
typedef float f32x4 __attribute__((ext_vector_type(4)));

// async global->LDS, 16B per lane. LDS dest is wave-uniform base + lane*16.
__device__ __forceinline__ void gll16(const half_t* g, half_t* l) {
    __builtin_amdgcn_global_load_lds(
        (const __attribute__((address_space(1))) void*)g,
        (__attribute__((address_space(3))) void*)l, 16, 0, 0);
}

// counted-vmcnt wait + raw barrier (verified idiom; rule #18 hygiene).
#define VM_WAIT_BARRIER(N) do {                                   \
    asm volatile("s_waitcnt vmcnt(" #N ")" ::: "memory");         \
    __builtin_amdgcn_s_barrier();                                 \
    __builtin_amdgcn_sched_barrier(0);                            \
} while (0)

// ---------------------------------------------------------------------------
// MFMA implicit-GEMM conv v8 (UNCHANGED from round 8 — it worked: halo convs
// ~70 us inferred from dispatch accounting; round 8's regression was solely
// the edge_fix rewrite, reverted below to the round-5 proven form).
// Empirical law (r0-r7): wall = staged bytes / rate; rate ~4 TB/s at 6
// waves/CU, ~6 TB/s at 12 waves/CU (r2, m97). Cut bytes AND run 12 w/CU.
//  - Tile 128co x 128px, EIGHT waves (512 thr, wave = 64co x 32px) ->
//    392 blocks = 12.25 waves/CU.
//  - HALO path (KS==3 && S==1; Gram + stage-B convs): per ci-chunk stage a
//    flat 256-px halo ONCE (2 gll16/wave, 16KB, ring-2), serve all 9 taps
//    from LDS; per-tap validity -> cndmask 0 (flat-index wraps never chosen).
//    B staging 9x less. A: [flat=cc*9+tap][co][32] 8KB chunks, ring-4,
//    lookahead 3; vmcnt ladder derived from exact issue order.
//  - OLD path (S==2 or KS==1): per-tap B staging, ring-3, lookahead 2.
// 16B-slot swizzle on DMA SOURCE + ds_read (rule 21).
// Frag layout (16x16x32): A row=l&15, k=(l>>4)*8+j ; B col=l&15 same k;
// C/D col=l&15, row=(l>>4)*4+reg  [m89-verified].
// ---------------------------------------------------------------------------
template<int KS, int S, int PAD, int MODE>
__global__ __launch_bounds__(512)
void conv_big(const half_t* __restrict__ Ag, const half_t* __restrict__ Xh,
              float* __restrict__ outF, half_t* __restrict__ outH,
              const half_t* __restrict__ auxH, const float* __restrict__ auxF,
              int CA, int Cout, int Hin, int Win, int Hout, int Wout, int ptiles,
              float alpha, float beta, float delta, int relu1,
              const float* __restrict__ pscale, const float* __restrict__ pbias,
              const float* __restrict__ aux3, int relu2,
              const half_t* __restrict__ zpg, int edge_defer,
              float* __restrict__ out2F)
{
    constexpr bool HALO = (KS == 3 && S == 1);
    __shared__ __align__(16) half_t sm[32768];   // 64 KB: A 4x4096h + B/halo 16384h

    const int tid = threadIdx.x;
    const int wv = tid >> 6, ln = tid & 63;
    const int co0 = blockIdx.y * 128;
    const int wco = (wv & 1) * 64, wpx = (wv >> 1) * 32;
    (void)ptiles;

    // bijective XCD swizzle (m204)
    int bx;
    {
        const int nwg = gridDim.x;
        const int q = nwg >> 3, r8 = nwg & 7;
        const int xcd = blockIdx.x & 7, idx = blockIdx.x >> 3;
        bx = (xcd < r8 ? xcd * (q + 1) : r8 * (q + 1) + (xcd - r8) * q) + idx;
    }
    const int p0 = bx * 128;

    const int PHW1 = Hout * Wout;
    const int NPX  = PHW1 * 32;

    const int fr = ln & 15, q8 = ln >> 4;
    const int sx = (q8 ^ ((fr >> 1) & 3)) << 3;   // read swizzle (row%16-based)

    const int cpt   = CA >> 5;
    const int total = KS * KS * cpt;

    // per-lane output geometry (2 px-groups per wave)
    int eph[2], epw[2], en2[2];
#pragma unroll
    for (int t2 = 0; t2 < 2; ++t2) {
        int px = p0 + wpx + t2 * 16 + fr;         // < NPX (exact tiling)
        en2[t2] = px / PHW1; int rem = px - en2[t2] * PHW1;
        eph[t2] = rem / Wout; epw[t2] = rem - eph[t2] * Wout;
    }

    // A chunk: contiguous 8KB at flat*Cout*32, 1 gll16/wave (row = tid>>2)
    auto issueA = [&](int flat, int slot) {
        const int row = tid >> 2;
        const int ssw = ((tid & 3) ^ ((row >> 1) & 3)) << 3;
        gll16(Ag + ((size_t)flat * Cout + co0 + row) * 32 + ssw,
              sm + slot * 4096 + tid * 8);
    };

    f32x4 acc[4][2] = {};

    if constexpr (HALO) {
        // halo: 256 px (p0-48 .. p0+207), 16KB, 2 gll16/wave
        auto issueH = [&](int cc, int hslot) {
            half_t* hb = sm + 16384 + hslot * 8192;
            const int c0 = cc << 5;
#pragma unroll
            for (int p = 0; p < 2; ++p) {
                const int hrow = (tid >> 2) + p * 128;
                const int hpx = p0 - 48 + hrow;
                const int ssw = ((tid & 3) ^ ((hrow >> 1) & 3)) << 3;
                const half_t* src = ((unsigned)hpx < (unsigned)NPX)
                    ? Xh + (size_t)hpx * CA + c0 + ssw : zpg;
                gll16(src, hb + p * 4096 + tid * 8);
            }
        };

        // prologue: H(0), A(0..2); need H0,A0 -> allow A1,A2
        issueH(0, 0);
        issueA(0, 0); issueA(1, 1); issueA(2, 2);
        VM_WAIT_BARRIER(2);

        int f = 0;
        for (int cc = 0; cc < cpt; ++cc) {
            half_t* hb = sm + 16384 + (cc & 1) * 8192;
            for (int ti = 0; ti < 9; ++ti, ++f) {
                half_t* ab = sm + (f & 3) * 4096;
                if (f + 3 < total) issueA(f + 3, (f + 3) & 3);
                const bool moreH = (ti == 4) && (cc + 1 < cpt);
                if (moreH) issueH(cc + 1, (cc + 1) & 1);

                const int kh = (ti * 11) >> 5, kw = ti - 3 * kh;
                const int dh = (MODE == 0) ? kh - 1 : 1 - kh;
                const int dw = (MODE == 0) ? kw - 1 : 1 - kw;
                const int doff = dh * Win + dw;

                half8 fa[4], fb[2];
#pragma unroll
                for (int m = 0; m < 4; ++m)
                    fa[m] = *(const half8*)(ab + (wco + m * 16 + fr) * 32 + sx);
#pragma unroll
                for (int t2 = 0; t2 < 2; ++t2) {
                    const int hidx = wpx + t2 * 16 + fr + 48 + doff;
                    half8 v = *(const half8*)(hb + hidx * 32 +
                                 ((q8 ^ ((hidx >> 1) & 3)) << 3));
                    bool ok = (unsigned)(eph[t2] + dh) < (unsigned)Hin &&
                              (unsigned)(epw[t2] + dw) < (unsigned)Win;
                    half8 z = {};
                    fb[t2] = ok ? v : z;
                }
#pragma unroll
                for (int m = 0; m < 4; ++m)
#pragma unroll
                    for (int t2 = 0; t2 < 2; ++t2)
                        acc[m][t2] = __builtin_amdgcn_mfma_f32_16x16x32_f16(
                            fa[m], fb[t2], acc[m][t2], 0, 0, 0);

                // end-of-step wait: chunk f+1 (and, by queue order, halo)
                const int nA = (f + 3 < total) ? 2 : ((f + 2 < total) ? 1 : 0);
                if (ti >= 4 && ti <= 6 && cc + 1 < cpt) VM_WAIT_BARRIER(4);
                else if (nA == 2)                        VM_WAIT_BARRIER(2);
                else if (nA == 1)                        VM_WAIT_BARRIER(1);
                else if (f + 1 < total)                  VM_WAIT_BARRIER(0);
            }
        }
    } else {
        // OLD path: per-tap B staging (1 gll16/wave), ring-3, lookahead 2
        const int brow = tid >> 2;
        int bpx = p0 + brow;                      // < NPX
        int bn2 = bpx / PHW1; int brem = bpx - bn2 * PHW1;
        const int bph = brem / Wout, bpw = brem - (brem / Wout) * Wout;
        const size_t bnb = (size_t)bn2 * Hin * Win;

        auto issueB = [&](int flat, int slot) {
            int cc, ti;
            if (KS == 1) { cc = flat; ti = 0; }
            else         { cc = (flat * 57) >> 9; ti = flat - 9 * cc; }
            const int kh = (KS == 3) ? ((ti * 11) >> 5) : 0;
            const int kw = (KS == 3) ? (ti - 3 * kh) : 0;
            const int c0 = cc << 5;
            const int hh = bph * S - PAD + kh, ww2 = bpw * S - PAD + kw;
            const bool ok = (unsigned)hh < (unsigned)Hin &&
                            (unsigned)ww2 < (unsigned)Win;
            const int ssw = ((tid & 3) ^ ((brow >> 1) & 3)) << 3;
            const half_t* src = ok
                ? Xh + (bnb + (size_t)(hh * Win + ww2)) * CA + c0 + ssw : zpg;
            gll16(src, sm + 16384 + slot * 4096 + tid * 8);
        };

        issueA(0, 0); issueB(0, 0);
        issueA(1, 1); issueB(1, 1);
        VM_WAIT_BARRIER(2);

        for (int k = 0; k < total; ++k) {
            half_t* ab = sm + (k % 3) * 4096;
            half_t* bb = sm + 16384 + (k % 3) * 4096;
            if (k + 2 < total) { issueA(k + 2, (k + 2) % 3); issueB(k + 2, (k + 2) % 3); }
            half8 fa[4], fb[2];
#pragma unroll
            for (int m = 0; m < 4; ++m)
                fa[m] = *(const half8*)(ab + (wco + m * 16 + fr) * 32 + sx);
#pragma unroll
            for (int t2 = 0; t2 < 2; ++t2)
                fb[t2] = *(const half8*)(bb + (wpx + t2 * 16 + fr) * 32 + sx);
#pragma unroll
            for (int m = 0; m < 4; ++m)
#pragma unroll
                for (int t2 = 0; t2 < 2; ++t2)
                    acc[m][t2] = __builtin_amdgcn_mfma_f32_16x16x32_f16(
                        fa[m], fb[t2], acc[m][t2], 0, 0, 0);
            if (k + 2 < total)      VM_WAIT_BARRIER(2);
            else if (k + 1 < total) VM_WAIT_BARRIER(0);
        }
    }

    // epilogue: wave 64co x 32px; lane 2x4x4 = 32 outputs
#pragma unroll
    for (int t = 0; t < 2; ++t) {
        const int oh = eph[t], ow = epw[t], n2 = en2[t];
        size_t ghwc = ((size_t)(n2 * Hout + oh) * Wout + ow) * Cout;
        bool defer = edge_defer && (oh == 0 || ow == 0);
#pragma unroll
        for (int m = 0; m < 4; ++m) {
#pragma unroll
            for (int rr = 0; rr < 4; ++rr) {
                int co_l = co0 + wco + m * 16 + q8 * 4 + rr;
                size_t fidx = ((size_t)(n2 * Cout + co_l) * Hout + oh) * Wout + ow;
                float av = alpha * acc[m][t][rr];
                if (out2F) out2F[fidx] = av;
                float v = av + delta;
                if (auxH) v += beta * (float)auxH[ghwc + co_l];
                if (auxF) v += beta * auxF[fidx];
                if (!defer) {
                    if (relu1) v = fmaxf(v, 0.f);
                    if (pscale) v = pscale[co_l] * v + pbias[co_l];
                    if (aux3) v += aux3[fidx];
                    if (relu2) v = fmaxf(v, 0.f);
                }
                if (outH) outH[ghwc + co_l] = (half_t)v;
                else      outF[fidx] = v;
            }
        }
    }
}

// pack weights into [ci-chunk*KT+tap][co][32ci] (+ transpose for convT).
template<int KT>
__global__ __launch_bounds__(256)
void pack_w(const float* __restrict__ W, half_t* __restrict__ Wh,
            half_t* __restrict__ WTh, int Cin, int Cout, int do_norm)
{
    __shared__ float red[256];
    int co = blockIdx.x, tid = threadIdx.x;
    int CK = Cin * KT;
    const float* w = W + (size_t)co * CK;
    float inv = 1.f;
    if (do_norm) {
        float s = 0.f;
        for (int i = tid; i < CK; i += 256) { float v = w[i]; s += v * v; }
        red[tid] = s; __syncthreads();
        for (int o = 128; o > 0; o >>= 1) {
            if (tid < o) red[tid] += red[tid + o];
            __syncthreads();
        }
        inv = 1.f / (sqrtf(red[0]) + 1e-12f);
    }
    for (int i = tid; i < CK; i += 256) {
        int ci = i / KT, tap = i - ci * KT;
        half_t h = (half_t)(w[i] * inv);
        Wh[(((size_t)(ci >> 5) * KT + tap) * Cout + co) * 32 + (ci & 31)] = h;
        if (WTh) WTh[(((size_t)(co >> 5) * KT + tap) * Cin + ci) * 32 + (co & 31)] = h;
    }
}

// Gram precompute (round 5): Gp in [b-chunk*9+tap][co][32b]; edge tensors.
__global__ __launch_bounds__(256)
void gram_kernel(const half_t* __restrict__ Wh, half_t* __restrict__ Gp,
                 half_t* __restrict__ ChT, half_t* __restrict__ CwT,
                 half_t* __restrict__ CcT)
{
    __shared__ float Wa[9 * 128];
    int co = blockIdx.x, b = threadIdx.x;
    for (int i = b; i < 9 * 128; i += 256) Wa[i] = (float)Wh[(size_t)co * 9 * 128 + i];
    __syncthreads();
    const half_t* Wb = Wh + (size_t)b * 9 * 128;
    auto dot = [&](int tA, int tB) {
        float s = 0.f;
        for (int c = 0; c < 128; ++c) s += Wa[tA * 128 + c] * (float)Wb[tB * 128 + c];
        return s;
    };
    auto lo = [](int t) { return (t == 2) ? 2 : 0; };
    auto hi = [](int t) { return (t == 1) ? 3 : ((t == 2) ? 3 : 1); };
    for (int th = 0; th < 3; ++th)
        for (int tw = 0; tw < 3; ++tw) {
            float s = 0.f;
            for (int kh = lo(th); kh < hi(th); ++kh)
                for (int kw = lo(tw); kw < hi(tw); ++kw)
                    s += dot(kh * 3 + kw, (kh + 2 - 2 * th) * 3 + (kw + 2 - 2 * tw));
            Gp[(((size_t)(b >> 5) * 9 + th * 3 + tw) * 256 + co) * 32 + (b & 31)] = (half_t)s;
        }
    for (int tw = 0; tw < 3; ++tw) {
        float s = 0.f, s2 = 0.f;
        for (int k = lo(tw); k < hi(tw); ++k) {
            s  += dot(k, k + 2 - 2 * tw);
            s2 += dot(k * 3, (k + 2 - 2 * tw) * 3);
        }
        ChT[((size_t)tw * 256 + b) * 256 + co] = (half_t)s;
        CwT[((size_t)tw * 256 + b) * 256 + co] = (half_t)s2;
    }
    CcT[(size_t)b * 256 + co] = (half_t)dot(0, 0);
}

// raw [co][tap][ci] normalized pack (gram input only)
__global__ __launch_bounds__(256)
void pack_raw(const float* __restrict__ W, half_t* __restrict__ Wr, int CK)
{
    __shared__ float red[256];
    int co = blockIdx.x, tid = threadIdx.x;
    const float* w = W + (size_t)co * CK;
    float s = 0.f;
    for (int i = tid; i < CK; i += 256) { float v = w[i]; s += v * v; }
    red[tid] = s; __syncthreads();
    for (int o = 128; o > 0; o >>= 1) {
        if (tid < o) red[tid] += red[tid + o];
        __syncthreads();
    }
    float inv = 1.f / (sqrtf(red[0]) + 1e-12f);
    for (int i = tid; i < CK; i += 256) {
        int ci = i / 9, tap = i - ci * 9;
        Wr[((size_t)co * 9 + tap) * (CK / 9) + ci] = (half_t)(w[i] * inv);
    }
}

// finish boundary px (oh==0 || ow==0) of a Gram-conv output — ROUND-5 PROVEN
// FORM (grid (55, 32), block 256 = co; r8's 55-block n-loop rewrite was a
// 60x regression: 0.2 blocks/CU + serial scalar broadcast chain).
__global__ __launch_bounds__(256)
void edge_fix(const half_t* __restrict__ a, half_t* out,
              const half_t* __restrict__ ChT, const half_t* __restrict__ CwT,
              const half_t* __restrict__ CcT,
              const float* __restrict__ ps, const float* __restrict__ pb)
{
    int i = blockIdx.x, n = blockIdx.y, co = threadIdx.x;
    int oh, ow;
    if (i < 28) { oh = 0; ow = i; } else { oh = i - 27; ow = 0; }
    float corr = 0.f;
    if (oh == 0) {
        for (int kw = 0; kw < 3; ++kw) {
            int pw = ow - 1 + kw;
            if ((unsigned)pw < 28u) {
                const half_t* ap = a + ((size_t)(n * 28 + 0) * 28 + pw) * 256;
                const half_t* cp = ChT + (size_t)kw * 256 * 256 + co;
                for (int b2 = 0; b2 < 256; ++b2)
                    corr += (float)cp[(size_t)b2 * 256] * (float)ap[b2];
            }
        }
    }
    if (ow == 0) {
        for (int kh = 0; kh < 3; ++kh) {
            int ph = oh - 1 + kh;
            if ((unsigned)ph < 28u) {
                const half_t* ap = a + ((size_t)(n * 28 + ph) * 28 + 0) * 256;
                const half_t* cp = CwT + (size_t)kh * 256 * 256 + co;
                for (int b2 = 0; b2 < 256; ++b2)
                    corr += (float)cp[(size_t)b2 * 256] * (float)ap[b2];
            }
        }
    }
    if (oh == 0 && ow == 0) {
        const half_t* ap = a + ((size_t)(n * 28) * 28) * 256;
        for (int b2 = 0; b2 < 256; ++b2)
            corr -= (float)CcT[(size_t)b2 * 256 + co] * (float)ap[b2];
    }
    size_t idx = ((size_t)(n * 28 + oh) * 28 + ow) * 256 + co;
    float v = (float)out[idx] + MU_F * corr;
    v = fmaxf(v, 0.f);
    if (ps) v = ps[co] * v + pb[co];
    out[idx] = (half_t)v;
}

__global__ __launch_bounds__(256)
void tx_kernel(const float* __restrict__ x, half_t* __restrict__ xTh)
{
    __shared__ __align__(16) half_t tl[56 * 136];
    int h = blockIdx.x, n = blockIdx.y, tid = threadIdx.x;
    for (int it = 0; it < 28; ++it) {
        int id = tid + it * 256;
        int c = id / 56, w0 = id - c * 56;
        tl[w0 * 136 + c] = (half_t)x[(((size_t)n * 128 + c) * 56 + h) * 56 + w0];
    }
    __syncthreads();
    if (tid < 224) {
        int w0 = tid >> 2, part = tid & 3;
        size_t base = (((size_t)n * 56 + h) * 56 + w0) * 128 + part * 32;
#pragma unroll
        for (int j = 0; j < 4; ++j)
            *(half8*)(xTh + base + j * 8) = *(const half8*)(tl + w0 * 136 + part * 32 + j * 8);
    }
}

__global__ __launch_bounds__(256)
void comb_kernel(const half_t* __restrict__ c, const half_t* __restrict__ p,
                 half_t* __restrict__ a, float w1, float w2, int n8)
{
    int i = blockIdx.x * 256 + threadIdx.x;
    if (i >= n8) return;
    half8 cv = ((const half8*)c)[i];
    half8 pv = ((const half8*)p)[i];
    half8 rres;
#pragma unroll
    for (int j = 0; j < 8; ++j) rres[j] = (half_t)(w1 * (float)cv[j] + w2 * (float)pv[j]);
    ((half8*)a)[i] = rres;
}

__global__ __launch_bounds__(256)
void bn_prep_kernel(const float* __restrict__ g, const float* __restrict__ b,
                    const float* __restrict__ m, const float* __restrict__ v,
                    float* __restrict__ s, float* __restrict__ t, int C)
{
    int i = blockIdx.x * 256 + threadIdx.x;
    if (i < C) {
        float sc = g[i] * rsqrtf(v[i] + BN_EPS_F);
        s[i] = sc; t[i] = b[i] - m[i] * sc;
    }
}

__global__ __launch_bounds__(128)
void zfill_kernel(half_t* __restrict__ p)
{
    p[threadIdx.x] = (half_t)0.f;
}

extern "C" void kernel_launch(void* const* d_in, const int* in_sizes, int n_in,
                              void* d_out, int out_size, void* d_ws, size_t ws_size,
                              hipStream_t stream)
{
    (void)in_sizes; (void)n_in; (void)out_size;
    const float* x    = (const float*)d_in[0];
    const float* W1   = (const float*)d_in[1];
    const float* W2   = (const float*)d_in[2];
    const float* Wsc  = (const float*)d_in[3];
    const float* bn1g = (const float*)d_in[4];
    const float* bn1b = (const float*)d_in[5];
    const float* bn1m = (const float*)d_in[6];
    const float* bn1v = (const float*)d_in[7];
    const float* bn2g = (const float*)d_in[8];
    const float* bn2b = (const float*)d_in[9];
    const float* bn2m = (const float*)d_in[10];
    const float* bn2v = (const float*)d_in[11];
    const float* bscg = (const float*)d_in[12];
    const float* bscb = (const float*)d_in[13];
    const float* bscm = (const float*)d_in[14];
    const float* bscv = (const float*)d_in[15];

    const size_t NB = (size_t)32 * 256 * 28 * 28;
    const size_t NX = (size_t)32 * 128 * 56 * 56;

    char* base = (char*)d_ws;
    size_t off = 0;
    auto alloc = [&](size_t nbytes) -> void* {
        void* r = base + off;
        off = (off + nbytes + 255) & ~(size_t)255;
        return r;
    };
    half_t* Wh1  = (half_t*)alloc(294912 * 2);
    half_t* Wr1  = (half_t*)alloc(294912 * 2);
    half_t* Wh2  = (half_t*)alloc(589824 * 2);
    half_t* WTh2 = (half_t*)alloc(589824 * 2);
    half_t* Wsch = (half_t*)alloc(32768 * 2);
    half_t* Gph  = (half_t*)alloc(589824 * 2);
    half_t* ChT  = (half_t*)alloc(196608 * 2);
    half_t* CwT  = (half_t*)alloc(196608 * 2);
    half_t* CcT  = (half_t*)alloc(65536 * 2);
    float* bn1s = (float*)alloc(256 * 4);  float* bn1t = (float*)alloc(256 * 4);
    float* bn2s = (float*)alloc(256 * 4);  float* bn2t = (float*)alloc(256 * 4);
    float* bscs = (float*)alloc(256 * 4);  float* bsct = (float*)alloc(256 * 4);
    half_t* zpg  = (half_t*)alloc(256);
    half_t* xTh  = (half_t*)alloc(NX * 2);
    half_t* Pa   = (half_t*)alloc(NB * 2);
    half_t* Pb   = (half_t*)alloc(NB * 2);
    half_t* Pc   = (half_t*)alloc(NB * 2);
    half_t* Py   = (half_t*)alloc(NB * 2);
    half_t* r28h = (half_t*)alloc(NB * 2);
    float*  scF  = (float*)alloc(NB * 4);
    if (off > ws_size) return;

    float*  cxF = (float*)Py;    // fp32 NCHW cache over Py+r28h (dead in stage A)
    half_t* Pd  = (half_t*)xTh;  // stage-B temp over xTh (dead in stage B)

    float* outp = (float*)d_out;

    double t = 1.0; float al[3];
    for (int i = 0; i < 3; ++i) {
        double tn = (1.0 + sqrt(1.0 + 4.0 * t * t)) / 2.0;
        al[i] = (float)((t - 1.0) / tn); t = tn;
    }

    const dim3 blk(256);
    const dim3 cblk(512);          // 8 waves
    const dim3 gB(196, 2, 1);      // 25088/128 px-tiles x 2 co-halves
    const dim3 gE(55, 32, 1);      // round-5 proven edge_fix grid
    const int n8 = (int)(NB / 8);
    const dim3 gC((n8 + 255) / 256);
    const float* NF = nullptr;
    const half_t* NH = nullptr;
    float* NFo = nullptr;
    half_t* NHo = nullptr;

    pack_w<9><<<256, blk, 0, stream>>>(W1, Wh1, nullptr, 128, 256, 1);
    pack_raw<<<256, blk, 0, stream>>>(W1, Wr1, 128 * 9);
    pack_w<9><<<256, blk, 0, stream>>>(W2, Wh2, WTh2, 256, 256, 1);
    pack_w<1><<<256, blk, 0, stream>>>(Wsc, Wsch, nullptr, 128, 256, 0);
    gram_kernel<<<256, blk, 0, stream>>>(Wr1, Gph, ChT, CwT, CcT);
    bn_prep_kernel<<<1, blk, 0, stream>>>(bn1g, bn1b, bn1m, bn1v, bn1s, bn1t, 256);
    bn_prep_kernel<<<1, blk, 0, stream>>>(bn2g, bn2b, bn2m, bn2v, bn2s, bn2t, 256);
    bn_prep_kernel<<<1, blk, 0, stream>>>(bscg, bscb, bscm, bscv, bscs, bsct, 256);
    zfill_kernel<<<1, dim3(128), 0, stream>>>(zpg);
    tx_kernel<<<dim3(56, 32), blk, 0, stream>>>(x, xTh);

    // ============ Stage A: dict_conv(x, W1, stride 2) — Gram form ==========
    conv_big<3,2,1,0><<<gB, cblk, 0, stream>>>(Wh1, xTh, NFo, Pa, NH, NF,
        128, 256, 56, 56, 28, 28, 196, MU_F, 0.f, -SHRINK_F, 1, NF, NF, NF, 0, zpg, 0, cxF);
    conv_big<1,2,0,0><<<gB, cblk, 0, stream>>>(Wsch, xTh, scF, NHo, NH, NF,
        128, 256, 56, 56, 28, 28, 196, 1.f, 0.f, 0.f, 0, bscs, bsct, NF, 0, zpg, 0, NFo);

    conv_big<3,1,1,0><<<gB, cblk, 0, stream>>>(Gph, Pa, NFo, Pb, Pa, cxF,
        256, 256, 28, 28, 28, 28, 196, -MU_F, 1.f, -SHRINK_F, 1, NF, NF, NF, 0, zpg, 1, NFo);
    edge_fix<<<gE, blk, 0, stream>>>(Pa, Pb, ChT, CwT, CcT, NF, NF);

    comb_kernel<<<gC, blk, 0, stream>>>(Pb, Pa, Pc, 1.f + al[1], -al[1], n8);
    conv_big<3,1,1,0><<<gB, cblk, 0, stream>>>(Gph, Pc, NFo, Pa, Pc, cxF,
        256, 256, 28, 28, 28, 28, 196, -MU_F, 1.f, -SHRINK_F, 1, NF, NF, NF, 0, zpg, 1, NFo);
    edge_fix<<<gE, blk, 0, stream>>>(Pc, Pa, ChT, CwT, CcT, NF, NF);

    comb_kernel<<<gC, blk, 0, stream>>>(Pa, Pb, Pc, 1.f + al[2], -al[2], n8);
    conv_big<3,1,1,0><<<gB, cblk, 0, stream>>>(Gph, Pc, NFo, Pb, Pc, cxF,
        256, 256, 28, 28, 28, 28, 196, -MU_F, 1.f, -SHRINK_F, 1, bn1s, bn1t, NF, 0, zpg, 1, NFo);
    edge_fix<<<gE, blk, 0, stream>>>(Pc, Pb, ChT, CwT, CcT, bn1s, bn1t);

    // ================= Stage B: dict_conv(y1=Pb, W2, stride 1) =============
    conv_big<3,1,1,0><<<gB, cblk, 0, stream>>>(Wh2, Pb, NFo, Pa, NH, NF,
        256, 256, 28, 28, 28, 28, 196, MU_F, 0.f, -SHRINK_F, 1, NF, NF, NF, 0, zpg, 0, NFo);

    conv_big<3,1,1,1><<<gB, cblk, 0, stream>>>(WTh2, Pa, NFo, r28h, Pb, NF,
        256, 256, 28, 28, 28, 28, 196, -1.f, 1.f, 0.f, 0, NF, NF, NF, 0, zpg, 0, NFo);
    conv_big<3,1,1,0><<<gB, cblk, 0, stream>>>(Wh2, r28h, NFo, Pd, Pa, NF,
        256, 256, 28, 28, 28, 28, 196, MU_F, 1.f, -SHRINK_F, 1, NF, NF, NF, 0, zpg, 0, NFo);

    comb_kernel<<<gC, blk, 0, stream>>>(Pd, Pa, Pc, 1.f + al[1], -al[1], n8);
    conv_big<3,1,1,1><<<gB, cblk, 0, stream>>>(WTh2, Pc, NFo, r28h, Pb, NF,
        256, 256, 28, 28, 28, 28, 196, -1.f, 1.f, 0.f, 0, NF, NF, NF, 0, zpg, 0, NFo);
    conv_big<3,1,1,0><<<gB, cblk, 0, stream>>>(Wh2, r28h, NFo, Pa, Pc, NF,
        256, 256, 28, 28, 28, 28, 196, MU_F, 1.f, -SHRINK_F, 1, NF, NF, NF, 0, zpg, 0, NFo);

    comb_kernel<<<gC, blk, 0, stream>>>(Pa, Pd, Pc, 1.f + al[2], -al[2], n8);
    conv_big<3,1,1,1><<<gB, cblk, 0, stream>>>(WTh2, Pc, NFo, r28h, Pb, NF,
        256, 256, 28, 28, 28, 28, 196, -1.f, 1.f, 0.f, 0, NF, NF, NF, 0, zpg, 0, NFo);
    conv_big<3,1,1,0><<<gB, cblk, 0, stream>>>(Wh2, r28h, outp, NHo, Pc, NF,
        256, 256, 28, 28, 28, 28, 196, MU_F, 1.f, -SHRINK_F, 1, bn2s, bn2t, scF, 1, zpg, 0, NFo);
}